// Round 2
// baseline (273.476 us; speedup 1.0000x reference)
//
#include <hip/hip_runtime.h>

#define LSIG 4096
#define OUTL 8191          // 2L-1
#define OFF  544           // zero pad each side (multiple of 8, covers loop overshoot)
#define LOGN (LSIG + 2*OFF)            // 5184 logical dwords
#define NPHYS 5832                     // >= phys(LOGN-1)+1 = 5828, rounded to /4

// swizzle: insert 4 pad dwords every 32 -> 8-aligned chunks stay contiguous &
// 16B-aligned; stride-8-dword lane patterns cover all 8 bank-quads per 8 lanes
__device__ __forceinline__ int phys(int l) { return l + ((l >> 5) << 2); }

__global__ __launch_bounds__(128)
void selfconv_kernel(const float* __restrict__ xg, float* __restrict__ outg) {
    __shared__ float buf[NPHYS];
    const int tid = threadIdx.x;
    const int b   = blockIdx.x >> 2;
    const int q   = blockIdx.x & 3;
    const float* __restrict__ xb = xg + b * LSIG;

    // zero whole LDS buffer (float4), then stage x at swizzled slots
    {
        float4* buf4 = (float4*)buf;
        for (int p = tid; p < NPHYS / 4; p += 128)
            buf4[p] = float4{0.f, 0.f, 0.f, 0.f};
    }
    __syncthreads();
    {
        const float4* xg4 = (const float4*)xb;
        for (int v = tid; v < LSIG / 4; v += 128) {
            int l = OFF + 4 * v;
            *(float4*)&buf[phys(l)] = xg4[v];
        }
    }
    __syncthreads();

    const int wave = tid >> 6;
    const int lane = tid & 63;
    const int s    = q * 2 + wave;   // 0..7

    // each wave: segment s (512 outputs) + segment s+8 (mirror) -> uniform work
    for (int half = 0; half < 2; ++half) {
        const int tW = 512 * s + half * 4096;
        const int t0 = tW + lane * 8;
        const int wb = t0 + OFF;

        int iLo = tW - (LSIG - 1); if (iLo < 0) iLo = 0;
        int iHi = tW + 511;        if (iHi > LSIG - 1) iHi = LSIG - 1;
        const int i0beg = iLo & ~7;
        int nch = (((iHi + 8) & ~7) - i0beg) >> 3;
        const int n3 = ((nch + 2) / 3) * 3;      // round trips to multiple of 3

        float acc[8];
#pragma unroll
        for (int j = 0; j < 8; ++j) acc[j] = 0.f;

        // window invariant at chunk i0: LO[m]=x[t0-i0-8+m], HI[m]=x[t0-i0+m]
        float W0[8], W1[8], W2[8], A0[8], A1[8], A2[8];
        {
            int l = wb - i0beg - 8;
            int p = phys(l);
            *(float4*)&W0[0] = *(const float4*)&buf[p];
            *(float4*)&W0[4] = *(const float4*)&buf[p + 4];
            int p2 = phys(l + 8);
            *(float4*)&W1[0] = *(const float4*)&buf[p2];
            *(float4*)&W1[4] = *(const float4*)&buf[p2 + 4];
        }
#pragma unroll
        for (int k = 0; k < 8; ++k) {
            int ik = i0beg + k;
            A0[k] = (ik < LSIG) ? xb[ik] : 0.f;
        }

        auto chunk = [&](float (&LO)[8], float (&HI)[8], float (&FR)[8],
                         float (&AC)[8], float (&AN)[8], int i0) {
            // prefetch next chunk's LO window (2x ds_read_b128)
            int l = wb - i0 - 16;
            int p = phys(l);
            float4 f0 = *(const float4*)&buf[p];
            float4 f1 = *(const float4*)&buf[p + 4];
            // prefetch next chunk's A (wave-uniform broadcast, global/L1 path)
#pragma unroll
            for (int k = 0; k < 8; ++k) {
                int ik = i0 + 8 + k;
                AN[k] = (ik < LSIG) ? xb[ik] : 0.f;
            }
            // 64 FMAs, all indices compile-time constant
#pragma unroll
            for (int k = 0; k < 8; ++k) {
                float a = AC[k];
#pragma unroll
                for (int j = 0; j < 8; ++j) {
                    int m = 8 + j - k;                 // in [1,15]
                    float wv = (m >= 8) ? HI[m - 8] : LO[m];
                    acc[j] += a * wv;
                }
            }
            // commit prefetched window (pure SSA rename after full unroll)
            FR[0] = f0.x; FR[1] = f0.y; FR[2] = f0.z; FR[3] = f0.w;
            FR[4] = f1.x; FR[5] = f1.y; FR[6] = f1.z; FR[7] = f1.w;
        };

        int i0 = i0beg;
        for (int c = 0; c < n3; c += 3) {
            chunk(W0, W1, W2, A0, A1, i0);
            chunk(W2, W0, W1, A1, A2, i0 + 8);
            chunk(W1, W2, W0, A2, A0, i0 + 16);
            i0 += 24;
        }

        float* ob = outg + b * OUTL;
#pragma unroll
        for (int j = 0; j < 8; ++j) {
            if (t0 + j < OUTL) ob[t0 + j] = acc[j];
        }
    }
}

extern "C" void kernel_launch(void* const* d_in, const int* in_sizes, int n_in,
                              void* d_out, int out_size, void* d_ws, size_t ws_size,
                              hipStream_t stream) {
    const float* x = (const float*)d_in[0];
    float* out = (float*)d_out;
    selfconv_kernel<<<dim3(512), dim3(128), 0, stream>>>(x, out);
}

// Round 3
// 75.892 us; speedup vs baseline: 3.6035x; 3.6035x over previous
//
#include <hip/hip_runtime.h>

#define LL   4096
#define OUTL 8191
#define PAD  1024
#define NPAIR 3072            // (LL + 2*PAD) / 2 pairs per copy
#define COPY_STRIDE 3848      // dwords per copy slot (3840 used + 8 bank stagger)
#define LDS_DW (3*COPY_STRIDE + 3840)   // 15384 dwords = 61536 B

typedef short v8s __attribute__((ext_vector_type(8)));
typedef float v4f __attribute__((ext_vector_type(4)));

__device__ __forceinline__ unsigned bf16b(float f) {
    unsigned u = __builtin_bit_cast(unsigned, f);
    u += 0x7fff + ((u >> 16) & 1);          // RNE
    return u >> 16;
}
__device__ __forceinline__ int physdw(int r, int p) {   // pair p of copy r -> dword
    return r * COPY_STRIDE + p + 2 * (p >> 3);
}
__device__ __forceinline__ unsigned ror16(unsigned x) { return (x >> 16) | (x << 16); }
__device__ __forceinline__ v8s mk8(uint2 lo, uint2 hi) {
    union { unsigned u[4]; v8s s; } z;
    z.u[0] = lo.x; z.u[1] = lo.y; z.u[2] = hi.x; z.u[3] = hi.y;
    return z.s;
}

struct Frag { uint2 a0l, a0h, a1l, a1h, b0l, b0h, b1l, b1h; };

__global__ __launch_bounds__(256)
void selfconv_mfma(const float* __restrict__ xg, float* __restrict__ outg) {
    __shared__ unsigned lds[LDS_DW];
    const int tid = threadIdx.x;
    const int b   = blockIdx.x >> 1;
    const int h   = blockIdx.x & 1;
    const float* __restrict__ xb = xg + b * LL;

    // ---- stage 4 parity-shifted bf16 copies of zero-padded x ----
    for (int r = 0; r < 4; ++r)
        for (int p = tid; p < NPAIR; p += 256) {
            int e0 = 2 * p + r - PAD;
            float f0 = (e0 >= 0 && e0 < LL) ? xb[e0] : 0.f;
            int e1 = e0 + 1;
            float f1 = (e1 >= 0 && e1 < LL) ? xb[e1] : 0.f;
            lds[physdw(r, p)] = bf16b(f0) | (bf16b(f1) << 16);
        }
    __syncthreads();

    const int wv   = tid >> 6;
    const int lane = tid & 63;
    const int ln16 = lane & 15;
    const int q    = lane >> 4;

    // balanced mega-tile permutation: each block's 4 waves sum to equal work
    const int perm0[4] = {0, 3, 5, 6};
    const int perm1[4] = {1, 2, 4, 7};
    const int M  = h ? perm1[wv] : perm0[wv];
    const int T0 = M << 10;

    // i0 loop bounds = union of the 4 accumulator tiles' needs
    int mn = 0x7fffffff, mx = -0x7fffffff;
#pragma unroll
    for (int u = 0; u < 2; ++u)
#pragma unroll
        for (int v = 0; v < 2; ++v) {
            int base = T0 + 256 * u + 512 * v;
            int iLo = base - (LL - 1); if (iLo < 0) iLo = 0;
            int iHi = base + 255;      if (iHi > LL - 1) iHi = LL - 1;
            int a = iLo - 256 * u; if (a < mn) mn = a;
            int c = iHi - 256 * u; if (c > mx) mx = c;
        }
    const int i0start = (mn - 15) & ~31;
    const int nch = ((mx - 31 - i0start + 31) >> 5) + 1;

    // fragment base addresses (dword indices into lds)
    int awA0, awA1, bw0, bw1;
    {
        int sA = i0start + ln16 + 8 * q;          // A_0 ascending start (m = ln16)
        int uA = sA + PAD;
        int rA = uA & 3, pA = (uA >> 2) << 1;
        awA0 = physdw(rA, pA); awA1 = physdw(rA, pA + 2);
        int sB = (T0 - i0start) - 7 - 8 * q + 16 * ln16;  // B_0 ascending start (n = ln16)
        int uB = sB + PAD;
        int rB = uB & 3, pB = (uB >> 2) << 1;
        bw0 = physdw(rB, pB); bw1 = physdw(rB, pB + 2);
    }
    // A_1 = A_0 + 256 elems -> +160 dw; B_1 = B_0 + 512 elems -> +320 dw (exact)

    v4f acc00 = {0,0,0,0}, acc01 = {0,0,0,0}, acc10 = {0,0,0,0}, acc11 = {0,0,0,0};

    auto loadF = [&](Frag& F) {
        F.a0l = *(const uint2*)&lds[awA0];
        F.a0h = *(const uint2*)&lds[awA1];
        F.a1l = *(const uint2*)&lds[awA0 + 160];
        F.a1h = *(const uint2*)&lds[awA1 + 160];
        F.b0l = *(const uint2*)&lds[bw0];
        F.b0h = *(const uint2*)&lds[bw1];
        F.b1l = *(const uint2*)&lds[bw0 + 320];
        F.b1h = *(const uint2*)&lds[bw1 + 320];
    };
    auto adv = [&]() { awA0 += 20; awA1 += 20; bw0 -= 20; bw1 -= 20; };
    auto compute = [&](const Frag& F) {
        v8s A0 = mk8(F.a0l, F.a0h);
        v8s A1 = mk8(F.a1l, F.a1h);
        // reverse 8 bf16 (descending k order): dw[j] = ror16(raw dword[3-j])
        uint2 r0l, r0h, r1l, r1h;
        r0l.x = ror16(F.b0h.y); r0l.y = ror16(F.b0h.x);
        r0h.x = ror16(F.b0l.y); r0h.y = ror16(F.b0l.x);
        r1l.x = ror16(F.b1h.y); r1l.y = ror16(F.b1h.x);
        r1h.x = ror16(F.b1l.y); r1h.y = ror16(F.b1l.x);
        v8s B0 = mk8(r0l, r0h);
        v8s B1 = mk8(r1l, r1h);
        acc00 = __builtin_amdgcn_mfma_f32_16x16x32_bf16(A0, B0, acc00, 0, 0, 0);
        acc01 = __builtin_amdgcn_mfma_f32_16x16x32_bf16(A0, B1, acc01, 0, 0, 0);
        acc10 = __builtin_amdgcn_mfma_f32_16x16x32_bf16(A1, B0, acc10, 0, 0, 0);
        acc11 = __builtin_amdgcn_mfma_f32_16x16x32_bf16(A1, B1, acc11, 0, 0, 0);
    };

    Frag F0, F1;
    loadF(F0); adv();
    int c = 0;
    for (; c + 2 <= nch; c += 2) {
        loadF(F1); adv();
        compute(F0);
        loadF(F0); adv();
        compute(F1);
    }
    if (c < nch) compute(F0);

    // ---- epilogue: D[m][n], m = 4q + reg, n = ln16; t = base_uv + m + 16n ----
    float* __restrict__ ob = outg + b * OUTL;
    const v4f* accs[4] = {&acc00, &acc10, &acc01, &acc11};  // [v*2+u] -> +256u+512v
#pragma unroll
    for (int uv = 0; uv < 4; ++uv) {
        int u = uv & 1, v = uv >> 1;
        int base = T0 + 256 * u + 512 * v + 4 * q + 16 * ln16;
        v4f a = *accs[uv];
#pragma unroll
        for (int r2 = 0; r2 < 4; ++r2) {
            int t = base + r2;
            if (t < OUTL) ob[t] = a[r2];
        }
    }
}

extern "C" void kernel_launch(void* const* d_in, const int* in_sizes, int n_in,
                              void* d_out, int out_size, void* d_ws, size_t ws_size,
                              hipStream_t stream) {
    const float* x = (const float*)d_in[0];
    float* out = (float*)d_out;
    selfconv_mfma<<<dim3(256), dim3(256), 0, stream>>>(x, out);
}

// Round 4
// 70.619 us; speedup vs baseline: 3.8725x; 1.0747x over previous
//
#include <hip/hip_runtime.h>

#define LL    4096
#define OUTL  8191
#define PAD   1024
#define NTOT  6144          // LL + 2*PAD
#define NPAIR 3072          // logical dwords (pairs) per forward copy
#define CSTR  3848          // phys dwords per forward copy (3840 + 8-bank stagger)
#define REVBASE 15392       // after 4 fwd copies (max phys 15381), 32-aligned
#define LDS_DW  (REVBASE + 3072)   // 18464 dwords = 73856 B

typedef short v8s __attribute__((ext_vector_type(8)));
typedef float v4f __attribute__((ext_vector_type(4)));

__device__ __forceinline__ unsigned bf16b(float f) {
    unsigned u = __builtin_bit_cast(unsigned, f);
    u += 0x7fff + ((u >> 16) & 1);          // RNE
    return u >> 16;
}
__device__ __forceinline__ int physdw(int r, int p) { return r * CSTR + p + 2 * (p >> 3); }
// reversed copy: 16B units, XOR swizzle spreads stride-8-dword lane patterns
__device__ __forceinline__ int revdw(int g) { return REVBASE + 4 * (g ^ ((g >> 3) & 7)); }

struct Frag { uint2 a0l, a0h, a1l, a1h; uint4 b0, b1; };

__global__ __launch_bounds__(512)
void selfconv_mfma2(const float* __restrict__ xg, float* __restrict__ outg) {
    __shared__ unsigned lds[LDS_DW];
    const int tid = threadIdx.x;
    const int b   = blockIdx.x >> 1;
    const int h   = blockIdx.x & 1;
    const float* __restrict__ xb = xg + b * LL;

    // ---- stage 4 parity-shifted forward bf16 copies ----
    for (int r = 0; r < 4; ++r)
        for (int p = tid; p < NPAIR; p += 512) {
            int e0 = 2 * p + r - PAD;
            int e1 = e0 + 1;
            float f0 = (e0 >= 0 && e0 < LL) ? xb[e0] : 0.f;
            float f1 = (e1 >= 0 && e1 < LL) ? xb[e1] : 0.f;
            lds[physdw(r, p)] = bf16b(f0) | (bf16b(f1) << 16);
        }
    // ---- stage reversed copy: yr[e] = y[6143-e], y = zero-padded x ----
    for (int g = tid; g < NTOT / 8; g += 512) {
        unsigned w[4];
#pragma unroll
        for (int d = 0; d < 4; ++d) {
            int xlo = 6143 - 8 * g - 2 * d - PAD;
            int xhi = xlo - 1;
            float flo = (xlo >= 0 && xlo < LL) ? xb[xlo] : 0.f;
            float fhi = (xhi >= 0 && xhi < LL) ? xb[xhi] : 0.f;
            w[d] = bf16b(flo) | (bf16b(fhi) << 16);
        }
        *(uint4*)&lds[revdw(g)] = uint4{w[0], w[1], w[2], w[3]};
    }
    __syncthreads();

    const int wv   = tid >> 6;
    const int lane = tid & 63;
    const int ln16 = lane & 15;
    const int q    = lane >> 4;
    const int tw   = wv & 3;
    const int half = wv >> 2;      // i-chunk parity split across wave pairs

    const int perm0[4] = {0, 3, 5, 6};     // balanced mega-tile permutation
    const int perm1[4] = {1, 2, 4, 7};
    const int M  = h ? perm1[tw] : perm0[tw];
    const int T0 = M << 10;

    int mn = 0x7fffffff, mx = -0x7fffffff;
#pragma unroll
    for (int u = 0; u < 2; ++u)
#pragma unroll
        for (int v = 0; v < 2; ++v) {
            int base = T0 + 256 * u + 512 * v;
            int iLo = base - (LL - 1); if (iLo < 0) iLo = 0;
            int iHi = base + 255;      if (iHi > LL - 1) iHi = LL - 1;
            int a = iLo - 256 * u; if (a < mn) mn = a;
            int c2 = iHi - 256 * u; if (c2 > mx) mx = c2;
        }
    const int base_   = mn - 15;
    const int i0start = base_ - ((base_ - 1) & 7);   // ≡ 1 (mod 8): B frags 16B-aligned
    const int nch     = ((mx - i0start) >> 5) + 1;
    const int nw      = (nch - half + 1) >> 1;       // this wave's chunk count

    const int i0w = i0start + 32 * half;
    // A fragment base (R3-proven): A[m][k=8q+j] = x[i0 + m + 8q + j]
    int uA = i0w + ln16 + 8 * q + PAD;
    int rA = uA & 3, pA = (uA >> 2) << 1;
    int awA0 = physdw(rA, pA), awA1 = physdw(rA, pA + 2);
    // B from reversed copy: B[8q+j][n] = yr[sR+j], sR = 5119 - T0 + i0 - 16n + 8q
    int gB = ((5119 - T0 + i0w) >> 3) - 2 * ln16 + q;

    v4f acc00{0,0,0,0}, acc01{0,0,0,0}, acc10{0,0,0,0}, acc11{0,0,0,0};

    auto loadF = [&](Frag& F) {
        F.a0l = *(const uint2*)&lds[awA0];
        F.a0h = *(const uint2*)&lds[awA1];
        F.a1l = *(const uint2*)&lds[awA0 + 160];   // +256 elements
        F.a1h = *(const uint2*)&lds[awA1 + 160];
        int d0 = revdw(gB);
        F.b0 = *(const uint4*)&lds[d0];
        F.b1 = *(const uint4*)&lds[d0 - 256];      // +512 fwd elements = -64 units
    };
    auto adv = [&]() { awA0 += 40; awA1 += 40; gB += 8; };  // 64 elements (2 chunks)
    auto mk8_2 = [](uint2 lo, uint2 hi) {
        union { unsigned u[4]; v8s s; } z;
        z.u[0] = lo.x; z.u[1] = lo.y; z.u[2] = hi.x; z.u[3] = hi.y; return z.s;
    };
    auto mk8_4 = [](uint4 v) {
        union { unsigned u[4]; v8s s; } z;
        z.u[0] = v.x; z.u[1] = v.y; z.u[2] = v.z; z.u[3] = v.w; return z.s;
    };
    auto compute = [&](const Frag& F) {
        v8s A0 = mk8_2(F.a0l, F.a0h);
        v8s A1 = mk8_2(F.a1l, F.a1h);
        v8s B0 = mk8_4(F.b0);
        v8s B1 = mk8_4(F.b1);
        acc00 = __builtin_amdgcn_mfma_f32_16x16x32_bf16(A0, B0, acc00, 0, 0, 0);
        acc01 = __builtin_amdgcn_mfma_f32_16x16x32_bf16(A0, B1, acc01, 0, 0, 0);
        acc10 = __builtin_amdgcn_mfma_f32_16x16x32_bf16(A1, B0, acc10, 0, 0, 0);
        acc11 = __builtin_amdgcn_mfma_f32_16x16x32_bf16(A1, B1, acc11, 0, 0, 0);
    };

    Frag F0, F1;
    if (nw > 0) loadF(F0);
    adv();
    int it = 0;
    for (; it + 2 <= nw; it += 2) {
        loadF(F1); adv();
        compute(F0);
        loadF(F0); adv();
        compute(F1);
    }
    if (it < nw) compute(F0);

    // ---- combine wave-pair partials through LDS (reuse staging region) ----
    __syncthreads();
    float* fs = (float*)lds;
    const int sb = (tw * 64 + lane) * 20;   // stride 20 dw breaks pow-2 banks
    if (half == 1) {
        *(v4f*)&fs[sb]      = acc00;
        *(v4f*)&fs[sb + 4]  = acc10;
        *(v4f*)&fs[sb + 8]  = acc01;
        *(v4f*)&fs[sb + 12] = acc11;
    }
    __syncthreads();
    if (half == 0) {
        acc00 += *(const v4f*)&fs[sb];
        acc10 += *(const v4f*)&fs[sb + 4];
        acc01 += *(const v4f*)&fs[sb + 8];
        acc11 += *(const v4f*)&fs[sb + 12];
        float* __restrict__ ob = outg + b * OUTL;
        const v4f* accs[4] = {&acc00, &acc10, &acc01, &acc11};
#pragma unroll
        for (int uv = 0; uv < 4; ++uv) {
            int u = uv & 1, v = uv >> 1;
            int t = T0 + 256 * u + 512 * v + 4 * q + 16 * ln16;
            v4f a = *accs[uv];
#pragma unroll
            for (int r2 = 0; r2 < 4; ++r2)
                if (t + r2 < OUTL) ob[t + r2] = a[r2];
        }
    }
}

extern "C" void kernel_launch(void* const* d_in, const int* in_sizes, int n_in,
                              void* d_out, int out_size, void* d_ws, size_t ws_size,
                              hipStream_t stream) {
    const float* x = (const float*)d_in[0];
    float* out = (float*)d_out;
    selfconv_mfma2<<<dim3(256), dim3(512), 0, stream>>>(x, out);
}